// Round 6
// baseline (256.678 us; speedup 1.0000x reference)
//
#include <hip/hip_runtime.h>

// SSIM loss, round 13: round-12 base (118us) + 4-column phase-2 tasks.
// imgs: (32, 3, 512, 512) fp32. Output: scalar 1 - mean(ssim_map).
//
// Occupancy model settled (r10/r12): launch_bounds never caps residency;
// HW places 7 blocks (LDS 22,528 x 7 = 157.7K <= 163.8K). 8 blocks would
// need union <= 20.4KB -> impossible with fp32 H. Occupancy lever closed.
// r11 lessons: v_pk_fma_f32 rate-neutral; device-scope fence = 1.3ms. Out.
//
// This round: phase 2 goes 2-col -> 4-col tasks (336 = 42 rows x 8 quads):
//   - 8 ds_read_b128 per task (16 slots c+2..c+17) amortized over 4 cols:
//     wave-level phase-2 reads 84 -> 48 per block (-43% on a ~60%-busy
//     LDS pipe with 52K conflict-cycles/CU).
//   - per-slot prep {ssum=fma(x,x,y*y), cr=x*y} = 3 instr, amortized over
//     ~4 consuming taps (was ~2) -> ~-80 VALU instr/thread.
//   - t-loop 3 -> 2 iterations; holds 2x4 v4f across the overlay barrier.
//
//  phase 1: stage 42x48 (x1,x2)-interleaved v2f tile (float4 global loads).
//  phase 2: 336 tasks; taps col c+j = slots c+3+j..c+13+j (k = i-1-j).
//  barrier; H (v4f[42][33]) OVERLAYS the staging union; 4 b128 writes/task.
//  phase 3: vertical blur, 4 consecutive rows/thread, one b128 read per dy,
//           SSIM with v_rcp_f32, wave reduce, spread atomics.

#define HH 512
#define WW 512
#define TILE 32
#define IN_ROWS 42
#define S_STRIDE 50         // v2f stride of s12 (even -> b128 alignment holds)
#define HSTRIDE 33          // v4f stride of H
#define NPLANES 96
#define NPIX 25165824.0f
#define NACC 256
#define NT2 336             // 42 rows * 8 col-quads

#define UNION_BYTES (IN_ROWS * HSTRIDE * 16)   // 22176 >= s12 (16800)

typedef float v2f __attribute__((ext_vector_type(2)));
typedef float v4f __attribute__((ext_vector_type(4)));

__global__ __launch_bounds__(256, 7) void ssim_fused_kernel(
    const float* __restrict__ img1, const float* __restrict__ img2,
    float* __restrict__ acc) {
  __shared__ __align__(16) char ub[UNION_BYTES];
  __shared__ float wsum[4];

  v2f (*s12)[S_STRIDE] = (v2f (*)[S_STRIDE])ub;
  v4f (*h)[HSTRIDE] = (v4f (*)[HSTRIDE])ub;

  const int tid = threadIdx.x;
  const int tx = blockIdx.x * TILE;
  const int ty = blockIdx.y * TILE;
  const size_t base = (size_t)blockIdx.z * (HH * WW);

  const float g[11] = {
      1.0283800e-03f, 7.5987600e-03f, 3.6000770e-02f, 1.0936072e-01f,
      2.1300560e-01f, 2.6601170e-01f, 2.1300560e-01f, 1.0936072e-01f,
      3.6000770e-02f, 7.5987600e-03f, 1.0283800e-03f};

  // ---- phase 1: float4 staging, interleave (x1,x2) into s12 ----
  // pixel slot = gx - (tx-8); 42 rows x 12 quads; quads 16B-aligned in global.
#pragma unroll
  for (int it = 0; it < 2; ++it) {
    int idx = it * 256 + tid;
    if (idx < IN_ROWS * 12) {
      int r = idx / 12;
      int p = idx - r * 12;
      int gy = ty - 5 + r;
      int gx = tx - 8 + 4 * p;
      v4f A = {0.f, 0.f, 0.f, 0.f}, B = {0.f, 0.f, 0.f, 0.f};
      if ((unsigned)gy < (unsigned)HH && (unsigned)gx < (unsigned)WW) {
        size_t off = base + (size_t)gy * WW + gx;
        A = *(const v4f*)(img1 + off);
        B = *(const v4f*)(img2 + off);
      }
      *(v4f*)&s12[r][4 * p]     = (v4f){A.x, B.x, A.y, B.y};
      *(v4f*)&s12[r][4 * p + 2] = (v4f){A.z, B.z, A.w, B.w};
    }
  }
  __syncthreads();

  // ---- phase 2: horizontal blur, 4 output cols per task ----
  // task (r, cq): c = 4*cq; read slots c+2..c+17 as 8 b128 (slot c+2 even
  // -> 16B aligned). Slot i (global slot c+2+i), i=1..14 carries taps:
  // col j uses k = i-1-j in [0,10].
  v4f hold[2][4];
#pragma unroll
  for (int t = 0; t < 2; ++t) {
    int idx = t * 256 + tid;
    if (idx < NT2) {
      int r = idx >> 3;
      int c = (idx & 7) << 2;
      const v4f* qp = (const v4f*)&s12[r][c + 2];   // 16B-aligned
      v2f P[16];
#pragma unroll
      for (int m = 0; m < 8; ++m) {
        v4f q = qp[m];
        P[2 * m]     = (v2f){q.x, q.y};
        P[2 * m + 1] = (v2f){q.z, q.w};
      }

      v2f a01[4], asc[4];
#pragma unroll
      for (int j = 0; j < 4; ++j) {
        a01[j] = (v2f){0.f, 0.f};
        asc[j] = (v2f){0.f, 0.f};
      }

#pragma unroll
      for (int i = 1; i <= 14; ++i) {
        v2f p = P[i];
        float cr = p.x * p.y;
        float ssum = __builtin_fmaf(p.x, p.x, p.y * p.y);
        v2f sc = (v2f){ssum, cr};
#pragma unroll
        for (int j = 0; j < 4; ++j) {
          int k = i - 1 - j;
          if (k >= 0 && k <= 10) {
            float w = g[k];
            a01[j] += w * p;
            asc[j] += w * sc;
          }
        }
      }
#pragma unroll
      for (int j = 0; j < 4; ++j)
        hold[t][j] = (v4f){a01[j].x, a01[j].y, asc[j].x, asc[j].y};
    }
  }
  __syncthreads();   // all s12 reads done; overlay H on the union

#pragma unroll
  for (int t = 0; t < 2; ++t) {
    int idx = t * 256 + tid;
    if (idx < NT2) {
      int r = idx >> 3;
      int c = (idx & 7) << 2;
#pragma unroll
      for (int j = 0; j < 4; ++j) h[r][c + j] = hold[t][j];
    }
  }
  __syncthreads();

  // ---- phase 3: vertical blur, 4 consecutive rows/thread ----
  const float C1 = 1e-4f;
  const float C2 = 9e-4f;
  const int c = tid & 31;
  const int r0 = (tid >> 5) * 4;

  v2f m[4], msc[4];
#pragma unroll
  for (int o = 0; o < 4; ++o) {
    m[o] = (v2f){0.f, 0.f};
    msc[o] = (v2f){0.f, 0.f};
  }

#pragma unroll
  for (int dy = 0; dy < 14; ++dy) {
    v4f q = h[r0 + dy][c];           // one ds_read_b128
    v2f a = (v2f){q.x, q.y};
    v2f sc = (v2f){q.z, q.w};
#pragma unroll
    for (int o = 0; o < 4; ++o) {
      const int k = dy - o;
      if (k >= 0 && k < 11) {
        float w = g[k];
        m[o] += w * a;
        msc[o] += w * sc;
      }
    }
  }

  float lsum = 0.f;
#pragma unroll
  for (int o = 0; o < 4; ++o) {
    float mu1 = m[o].x, mu2 = m[o].y;
    float S = msc[o].x, C = msc[o].y;
    float mu1sq = mu1 * mu1;
    float mu2sq = mu2 * mu2;
    float mu12 = mu1 * mu2;
    float sig12 = C - mu12;
    float sigs = S - mu1sq - mu2sq;  // sig11 + sig22
    float num = (2.f * mu12 + C1) * (2.f * sig12 + C2);
    float den = (mu1sq + mu2sq + C1) * (sigs + C2);
    lsum += num * __builtin_amdgcn_rcpf(den);
  }

  // wave reduction + one atomic per block into spread slots
#pragma unroll
  for (int off = 32; off > 0; off >>= 1)
    lsum += __shfl_down(lsum, off, 64);
  const int lane = tid & 63;
  const int wid = tid >> 6;
  if (lane == 0) wsum[wid] = lsum;
  __syncthreads();
  if (tid == 0) {
    float b = wsum[0] + wsum[1] + wsum[2] + wsum[3];
    int slot = (blockIdx.x + blockIdx.y * 16 + blockIdx.z) & (NACC - 1);
    atomicAdd(acc + slot, b);
  }
}

__global__ void ssim_finalize_kernel(const float* __restrict__ acc,
                                     float* __restrict__ out) {
  __shared__ float wsum[4];
  const int tid = threadIdx.x;
  float s = acc[tid];
#pragma unroll
  for (int off = 32; off > 0; off >>= 1)
    s += __shfl_down(s, off, 64);
  if ((tid & 63) == 0) wsum[tid >> 6] = s;
  __syncthreads();
  if (tid == 0)
    out[0] = 1.0f - (wsum[0] + wsum[1] + wsum[2] + wsum[3]) * (1.0f / NPIX);
}

extern "C" void kernel_launch(void* const* d_in, const int* in_sizes, int n_in,
                              void* d_out, int out_size, void* d_ws, size_t ws_size,
                              hipStream_t stream) {
  const float* img1 = (const float*)d_in[0];
  const float* img2 = (const float*)d_in[1];
  float* out = (float*)d_out;
  float* acc = (float*)d_ws;

  (void)hipMemsetAsync(acc, 0, NACC * sizeof(float), stream);

  dim3 grid(WW / TILE, HH / TILE, NPLANES);   // 16 x 16 x 96 = 24576
  ssim_fused_kernel<<<grid, 256, 0, stream>>>(img1, img2, acc);
  ssim_finalize_kernel<<<1, NACC, 0, stream>>>(acc, out);
}

// Round 7
// 250.443 us; speedup vs baseline: 1.0249x; 1.0249x over previous
//
#include <hip/hip_runtime.h>

// SSIM loss, round 14: REVERT to round-12 (verified best: 117.7us kernel,
// 248us e2e). Round-13's 4-col phase-2 regressed: conflicts 13.4M->18.4M
// (32B lane stride = 256B per 8 lanes = 0 mod 128B bank phase) outweighed
// the -10% VALU busy-time. 16B lane stride (2-col tasks) is conflict-minimal.
// imgs: (32, 3, 512, 512) fp32. Output: scalar 1 - mean(ssim_map).
//
// Closed levers (all empirically nulled this session):
//  - v_pk_fma_f32: rate-neutral on gfx950 (r11, busy-time conserved).
//  - occupancy: LDS fixes 7 blocks/CU; launch_bounds is not a cap (r12).
//  - tile 32x64: 3 blocks/CU -> VALUBusy 75->48 (r9).
//  - 4-col tasks: +5M conflicts (r13). merged finalize: fence = 1.3ms (r11).
//  - H stride permutes: conflict-insensitive (r8/r10).
//
//  phase 1: stage 42x48 (x1,x2)-interleaved v2f tile (float4 global loads).
//  phase 2: 672 tasks = 42 rows x 16 col-pairs; 7 ds_read_b128 per task;
//           per-slot {sq, sc={x^2+y^2, xy}} hoisting; 2 cols via shifted
//           weights; results held in registers across the barrier.
//  barrier; H (v4f[42][33]) OVERLAYS the staging union; 2 b128 writes/task.
//  phase 3: vertical blur, 4 consecutive rows/thread, one b128 read per dy,
//           SSIM with v_rcp_f32, wave reduce, spread atomics.

#define HH 512
#define WW 512
#define TILE 32
#define IN_ROWS 42
#define S_STRIDE 50         // v2f stride of s12 (even -> b128 alignment holds)
#define HSTRIDE 33          // v4f stride of H
#define NPLANES 96
#define NPIX 25165824.0f
#define NACC 256
#define NTASK 672           // 42 rows * 16 col-pairs

#define UNION_BYTES (IN_ROWS * HSTRIDE * 16)   // 22176 >= s12 (16800)

typedef float v2f __attribute__((ext_vector_type(2)));
typedef float v4f __attribute__((ext_vector_type(4)));

__global__ __launch_bounds__(256, 7) void ssim_fused_kernel(
    const float* __restrict__ img1, const float* __restrict__ img2,
    float* __restrict__ acc) {
  __shared__ __align__(16) char ub[UNION_BYTES];
  __shared__ float wsum[4];

  v2f (*s12)[S_STRIDE] = (v2f (*)[S_STRIDE])ub;
  v4f (*h)[HSTRIDE] = (v4f (*)[HSTRIDE])ub;

  const int tid = threadIdx.x;
  const int tx = blockIdx.x * TILE;
  const int ty = blockIdx.y * TILE;
  const size_t base = (size_t)blockIdx.z * (HH * WW);

  const float g[11] = {
      1.0283800e-03f, 7.5987600e-03f, 3.6000770e-02f, 1.0936072e-01f,
      2.1300560e-01f, 2.6601170e-01f, 2.1300560e-01f, 1.0936072e-01f,
      3.6000770e-02f, 7.5987600e-03f, 1.0283800e-03f};

  // ---- phase 1: float4 staging, interleave (x1,x2) into s12 ----
  // pixel slot = gx - (tx-8); 42 rows x 12 quads; quads 16B-aligned in global.
#pragma unroll
  for (int it = 0; it < 2; ++it) {
    int idx = it * 256 + tid;
    if (idx < IN_ROWS * 12) {
      int r = idx / 12;
      int p = idx - r * 12;
      int gy = ty - 5 + r;
      int gx = tx - 8 + 4 * p;
      v4f A = {0.f, 0.f, 0.f, 0.f}, B = {0.f, 0.f, 0.f, 0.f};
      if ((unsigned)gy < (unsigned)HH && (unsigned)gx < (unsigned)WW) {
        size_t off = base + (size_t)gy * WW + gx;
        A = *(const v4f*)(img1 + off);
        B = *(const v4f*)(img2 + off);
      }
      *(v4f*)&s12[r][4 * p]     = (v4f){A.x, B.x, A.y, B.y};
      *(v4f*)&s12[r][4 * p + 2] = (v4f){A.z, B.z, A.w, B.w};
    }
  }
  __syncthreads();

  // ---- phase 2: horizontal blur, 2 output cols per task, b128 tap reads ----
  // task (r, cp): c = 2*cp; taps for col c are pixel slots c+3..c+13,
  // for col c+1 slots c+4..c+14. Read slots c+2..c+15 as 7 b128.
  // Per-slot: sq = p*p, sc = {sq.x+sq.y, p.x*p.y}; both cols consume.
  v4f holdw[3][2];
#pragma unroll
  for (int t = 0; t < 3; ++t) {
    int idx = t * 256 + tid;
    if (idx < NTASK) {
      int r = idx >> 4;
      int c = (idx & 15) * 2;
      const v4f* qp = (const v4f*)&s12[r][c + 2];   // 16B-aligned
      v4f q0 = qp[0], q1 = qp[1], q2 = qp[2], q3 = qp[3];
      v4f q4 = qp[4], q5 = qp[5], q6 = qp[6];
      v2f P[14];
      P[0]  = (v2f){q0.x, q0.y};  P[1]  = (v2f){q0.z, q0.w};
      P[2]  = (v2f){q1.x, q1.y};  P[3]  = (v2f){q1.z, q1.w};
      P[4]  = (v2f){q2.x, q2.y};  P[5]  = (v2f){q2.z, q2.w};
      P[6]  = (v2f){q3.x, q3.y};  P[7]  = (v2f){q3.z, q3.w};
      P[8]  = (v2f){q4.x, q4.y};  P[9]  = (v2f){q4.z, q4.w};
      P[10] = (v2f){q5.x, q5.y};  P[11] = (v2f){q5.z, q5.w};
      P[12] = (v2f){q6.x, q6.y};  P[13] = (v2f){q6.z, q6.w};

      v2f a01_0 = (v2f){0.f, 0.f}, asc_0 = (v2f){0.f, 0.f};
      v2f a01_1 = (v2f){0.f, 0.f}, asc_1 = (v2f){0.f, 0.f};
#pragma unroll
      for (int k = 1; k <= 12; ++k) {
        v2f p = P[k];
        v2f sq = p * p;
        v2f sc = (v2f){sq.x + sq.y, p.x * p.y};
        if (k <= 11) {               // col0 taps slots 1..11, weight g[k-1]
          float w = g[k - 1];
          a01_0 += w * p;
          asc_0 += w * sc;
        }
        if (k >= 2) {                // col1 taps slots 2..12, weight g[k-2]
          float w = g[k - 2];
          a01_1 += w * p;
          asc_1 += w * sc;
        }
      }
      holdw[t][0] = (v4f){a01_0.x, a01_0.y, asc_0.x, asc_0.y};
      holdw[t][1] = (v4f){a01_1.x, a01_1.y, asc_1.x, asc_1.y};
    }
  }
  __syncthreads();   // all s12 reads done; overlay H on the union

#pragma unroll
  for (int t = 0; t < 3; ++t) {
    int idx = t * 256 + tid;
    if (idx < NTASK) {
      int r = idx >> 4;
      int c = (idx & 15) * 2;
      h[r][c]     = holdw[t][0];
      h[r][c + 1] = holdw[t][1];
    }
  }
  __syncthreads();

  // ---- phase 3: vertical blur, 4 consecutive rows/thread, 2 pk FMA/(dy,o) --
  const float C1 = 1e-4f;
  const float C2 = 9e-4f;
  const int c = tid & 31;
  const int r0 = (tid >> 5) * 4;

  v2f m[4], msc[4];
#pragma unroll
  for (int o = 0; o < 4; ++o) {
    m[o] = (v2f){0.f, 0.f};
    msc[o] = (v2f){0.f, 0.f};
  }

#pragma unroll
  for (int dy = 0; dy < 14; ++dy) {
    v4f q = h[r0 + dy][c];           // one ds_read_b128
    v2f a = (v2f){q.x, q.y};
    v2f sc = (v2f){q.z, q.w};
#pragma unroll
    for (int o = 0; o < 4; ++o) {
      const int k = dy - o;
      if (k >= 0 && k < 11) {
        float w = g[k];
        m[o] += w * a;
        msc[o] += w * sc;
      }
    }
  }

  float lsum = 0.f;
#pragma unroll
  for (int o = 0; o < 4; ++o) {
    float mu1 = m[o].x, mu2 = m[o].y;
    float S = msc[o].x, C = msc[o].y;
    float mu1sq = mu1 * mu1;
    float mu2sq = mu2 * mu2;
    float mu12 = mu1 * mu2;
    float sig12 = C - mu12;
    float sigs = S - mu1sq - mu2sq;  // sig11 + sig22
    float num = (2.f * mu12 + C1) * (2.f * sig12 + C2);
    float den = (mu1sq + mu2sq + C1) * (sigs + C2);
    lsum += num * __builtin_amdgcn_rcpf(den);
  }

  // wave reduction + one atomic per block into spread slots
#pragma unroll
  for (int off = 32; off > 0; off >>= 1)
    lsum += __shfl_down(lsum, off, 64);
  const int lane = tid & 63;
  const int wid = tid >> 6;
  if (lane == 0) wsum[wid] = lsum;
  __syncthreads();
  if (tid == 0) {
    float b = wsum[0] + wsum[1] + wsum[2] + wsum[3];
    int slot = (blockIdx.x + blockIdx.y * 16 + blockIdx.z) & (NACC - 1);
    atomicAdd(acc + slot, b);
  }
}

__global__ void ssim_finalize_kernel(const float* __restrict__ acc,
                                     float* __restrict__ out) {
  __shared__ float wsum[4];
  const int tid = threadIdx.x;
  float s = acc[tid];
#pragma unroll
  for (int off = 32; off > 0; off >>= 1)
    s += __shfl_down(s, off, 64);
  if ((tid & 63) == 0) wsum[tid >> 6] = s;
  __syncthreads();
  if (tid == 0)
    out[0] = 1.0f - (wsum[0] + wsum[1] + wsum[2] + wsum[3]) * (1.0f / NPIX);
}

extern "C" void kernel_launch(void* const* d_in, const int* in_sizes, int n_in,
                              void* d_out, int out_size, void* d_ws, size_t ws_size,
                              hipStream_t stream) {
  const float* img1 = (const float*)d_in[0];
  const float* img2 = (const float*)d_in[1];
  float* out = (float*)d_out;
  float* acc = (float*)d_ws;

  (void)hipMemsetAsync(acc, 0, NACC * sizeof(float), stream);

  dim3 grid(WW / TILE, HH / TILE, NPLANES);   // 16 x 16 x 96 = 24576
  ssim_fused_kernel<<<grid, 256, 0, stream>>>(img1, img2, acc);
  ssim_finalize_kernel<<<1, NACC, 0, stream>>>(acc, out);
}